// Round 8
// baseline (412.807 us; speedup 1.0000x reference)
//
#include <hip/hip_runtime.h>
#include <hip/hip_bf16.h>
#include <cstdint>
#include <cstddef>

#define Z 256      // latent dim (K); also bytes per fp8 row
#define CG 128     // e-columns per block
#define RT 64      // mean-rows per tile
#define NCH 16     // N chunks (grid = 64 x 16 = 1024 = 4 blocks/CU)
#define LOG2E 1.4426950408889634f
#define LN2 0.6931471805599453f

typedef __attribute__((ext_vector_type(4))) float f32x4;
typedef long long fp8v8;                                   // 8 fp8 = 2 VGPR
typedef __attribute__((ext_vector_type(2))) long long fp8v16;  // 16 fp8 = 4 VGPR

#define GLOAD_LDS16(g, l)                                                              \
  __builtin_amdgcn_global_load_lds((const __attribute__((address_space(1))) void*)(g), \
                                   (__attribute__((address_space(3))) void*)(l), 16, 0, 0)

__device__ __forceinline__ float fast_exp2(float x) {
#if __has_builtin(__builtin_amdgcn_exp2f)
  return __builtin_amdgcn_exp2f(x);
#else
  float r;
  asm("v_exp_f32 %0, %1" : "=v"(r) : "v"(x));
  return r;
#endif
}

// prep: fp32 -> fp8 e4m3 scaled by sqrt(c1), K-PERMUTED row layout
// (byte k -> pos 64*((k>>3)&3) + 8*(k>>5) + (k&7)), plus k2 * row-sum-of-squares.
// Lane handles k = lane32*8..+7 (all same h,kk) -> one 8B store at permuted pos.
__global__ __launch_bounds__(256) void prep_kernel(const float* __restrict__ mean,
                                                   const float* __restrict__ e,
                                                   unsigned char* __restrict__ Abf,
                                                   unsigned char* __restrict__ Bbf,
                                                   float* __restrict__ nrm,
                                                   const int* __restrict__ sigma_p,
                                                   int Nr, int Mr) {
  const float sgm = (float)(*sigma_p);
  const float c1 = LOG2E / (sgm * sgm);
  const float k2 = 0.5f * c1;
  const float sc = sqrtf(c1);
  const int tid = threadIdx.x;
  const int lane32 = tid & 31;
  const int row = blockIdx.x * 8 + (tid >> 5);
  if (row >= Nr + Mr) return;
  const float* src = (row < Nr) ? (mean + (size_t)row * Z) : (e + (size_t)(row - Nr) * Z);
  unsigned char* d = (row < Nr) ? (Abf + (size_t)row * Z) : (Bbf + (size_t)(row - Nr) * Z);
  const float4 v0 = *reinterpret_cast<const float4*>(src + lane32 * 8);
  const float4 v1 = *reinterpret_cast<const float4*>(src + lane32 * 8 + 4);
  float s = v0.x * v0.x + v0.y * v0.y + v0.z * v0.z + v0.w * v0.w +
            v1.x * v1.x + v1.y * v1.y + v1.z * v1.z + v1.w * v1.w;
  s += __shfl_xor(s, 1); s += __shfl_xor(s, 2); s += __shfl_xor(s, 4);
  s += __shfl_xor(s, 8); s += __shfl_xor(s, 16);
  if (lane32 == 0) nrm[row] = k2 * s;
  int r0 = __builtin_amdgcn_cvt_pk_fp8_f32(v0.x * sc, v0.y * sc, 0, false);
  r0 = __builtin_amdgcn_cvt_pk_fp8_f32(v0.z * sc, v0.w * sc, r0, true);
  int r1 = __builtin_amdgcn_cvt_pk_fp8_f32(v1.x * sc, v1.y * sc, 0, false);
  r1 = __builtin_amdgcn_cvt_pk_fp8_f32(v1.z * sc, v1.w * sc, r1, true);
  *reinterpret_cast<int2*>(d + ((lane32 & 3) << 6) + ((lane32 >> 2) << 3)) =
      make_int2(r0, r1);
}

// stage one full 64-row x 256-B fp8 A tile (16 KB) into buffer BUF (literal 0/1).
// LDS[r][p] = G[r][p ^ (r&7)] at 16B-slot granularity (linear LDS dest).
#define STAGE_TILE(BUF, T)                                  \
  {                                                         \
    const char* g = Ab8 + (size_t)(T) * 16384;              \
    GLOAD_LDS16(g + gof0, Sb + (BUF) * 16384 + o0);         \
    GLOAD_LDS16(g + gof1, Sb + (BUF) * 16384 + o1);         \
  }

// 32 MFMA for one tile from buffer BUF: 4 kk-pairs x (2 b128 reads + 8 MFMA).
// Read slot s at LDS slot s^(row&7): 16 lanes cover all 32 banks x2 (free).
#define COMPUTE_TILE(BUF)                                                             \
  {                                                                                   \
    _Pragma("unroll") for (int kp = 0; kp < 4; ++kp) {                                \
      fp8v16 at[2];                                                                   \
      const int slot = laneHi * 4 + kp;                                               \
      _Pragma("unroll") for (int a = 0; a < 2; ++a) {                                 \
        const int ro = wr * 32 + a * 16 + laneLo;                                     \
        at[a] = *reinterpret_cast<const fp8v16*>(                                     \
            Sb + (BUF) * 16384 + ro * 256 + ((slot ^ (ro & 7)) << 4));                \
      }                                                                               \
      _Pragma("unroll") for (int a = 0; a < 2; ++a)                                   \
          _Pragma("unroll") for (int c = 0; c < 2; ++c) {                             \
        acc[a][c] = __builtin_amdgcn_mfma_f32_16x16x32_fp8_fp8(                       \
            at[a][0], bfr[c][2 * kp],                                                 \
            (kp == 0) ? f32x4{0.f, 0.f, 0.f, 0.f} : acc[a][c], 0, 0, 0);              \
        acc[a][c] = __builtin_amdgcn_mfma_f32_16x16x32_fp8_fp8(                       \
            at[a][1], bfr[c][2 * kp + 1], acc[a][c], 0, 0, 0);                        \
      }                                                                               \
    }                                                                                 \
  }

// online-LSE over the finished tile: 8 logits/lane per col-frag (pre-scaled;
// per-column b2 term factored out -> applied in lse_finish)
#define EPILOGUE                                                                      \
  {                                                                                   \
    _Pragma("unroll") for (int c = 0; c < 2; ++c) {                                   \
      float w0 = acc[0][c][0] - av0.x, w1 = acc[0][c][1] - av0.y;                     \
      float w2 = acc[0][c][2] - av0.z, w3 = acc[0][c][3] - av0.w;                     \
      float w4 = acc[1][c][0] - av1.x, w5 = acc[1][c][1] - av1.y;                     \
      float w6 = acc[1][c][2] - av1.z, w7 = acc[1][c][3] - av1.w;                     \
      float mx = fmaxf(fmaxf(fmaxf(w0, w1), fmaxf(w2, w3)),                           \
                       fmaxf(fmaxf(w4, w5), fmaxf(w6, w7)));                          \
      float nm = fmaxf(m_run[c], mx);                                                 \
      float ss = fast_exp2(w0 - nm) + fast_exp2(w1 - nm) + fast_exp2(w2 - nm) +       \
                 fast_exp2(w3 - nm) + fast_exp2(w4 - nm) + fast_exp2(w5 - nm) +       \
                 fast_exp2(w6 - nm) + fast_exp2(w7 - nm);                             \
      s_run[c] = s_run[c] * fast_exp2(m_run[c] - nm) + ss;                            \
      m_run[c] = nm;                                                                  \
    }                                                                                 \
  }

#define ALOAD                                                  \
  av0 = *reinterpret_cast<const float4*>(aptr);                \
  av1 = *reinterpret_cast<const float4*>(aptr + 16);           \
  aptr += 64;

// Column-strip fused GEMM (fp8 e4m3, K-permuted) + online logsumexp.
// Full-tile double buffer (2x16 KB), one __syncthreads per tile.
// 8 waves (2r x 4c); B panel register-resident; 4 blocks/CU.
__global__ __launch_bounds__(512, 8) void gemm_lse_kernel(
    const unsigned char* __restrict__ Abf,  // [N][Z] fp8, scaled, K-permuted
    const unsigned char* __restrict__ Bbf,  // [M][Z] fp8
    const float* __restrict__ nrm,          // [N+M]: k2*a2 then k2*b2
    float2* __restrict__ part,              // [NCH][M] (max2, sumexp2), b2-uncorrected
    int Mtot, int chRows) {
  __shared__ __align__(16) char Sb[32768];  // B staged through it, then A dbuf

  const int tid = threadIdx.x;
  const int lane = tid & 63;
  const int w = tid >> 6;
  const int wr = w >> 2, wc = w & 3;
  const int laneLo = lane & 15, laneHi = lane >> 4;

  const int id = blockIdx.x;
  const int y = id & 15;   // XCD-affine: chunks y, y+8 pinned to xcd id&7
  const int x = id >> 4;
  const int row0base = y * chRows;
  const int col0 = x * CG;
  const int ntiles = chRows / RT;  // 32

  // ---- stage full B panel (128 cols x 256 B = 32 KB), swizzled source ----
#pragma unroll
  for (int i = 0; i < 4; ++i) {
    int o = i * 8192 + tid * 16;
    int r = o >> 8;
    int p = (o >> 4) & 15;
    GLOAD_LDS16((const char*)Bbf + (size_t)(col0 + r) * Z + ((p ^ (r & 7)) << 4),
                Sb + o);
  }
  __syncthreads();
  fp8v8 bfr[2][8];
#pragma unroll
  for (int c = 0; c < 2; ++c) {
    const int rb = wc * 32 + c * 16 + laneLo;
#pragma unroll
    for (int kp = 0; kp < 4; ++kp) {
      const int slot = laneHi * 4 + kp;
      fp8v16 v = *reinterpret_cast<const fp8v16*>(Sb + rb * 256 +
                                                  ((slot ^ (rb & 7)) << 4));
      bfr[c][2 * kp] = v[0];
      bfr[c][2 * kp + 1] = v[1];
    }
  }
  __syncthreads();  // bfr safely in regs before A-stages overwrite Sb

  // ---- per-thread A staging offsets (2 gload_lds per tile) ----
  const char* Ab8 = (const char*)Abf + (size_t)row0base * Z;
  const int o0 = tid * 16, o1 = 8192 + tid * 16;
  const int r_0 = o0 >> 8, p_0 = (o0 >> 4) & 15;
  const int r_1 = o1 >> 8, p_1 = (o1 >> 4) & 15;
  const int gof0 = r_0 * 256 + ((p_0 ^ (r_0 & 7)) << 4);
  const int gof1 = r_1 * 256 + ((p_1 ^ (r_1 & 7)) << 4);
  const float* aptr = nrm + row0base + wr * 32 + laneHi * 4;

  f32x4 acc[2][2];
  float m_run[2] = {-1e30f, -1e30f};
  float s_run[2] = {0.f, 0.f};
  float4 av0, av1;

  STAGE_TILE(0, 0);
  __syncthreads();  // tile 0 resident

  for (int tp = 0; tp < ntiles / 2; ++tp) {
    const int t = tp * 2;
    // even tile (buf 0); prefetch odd tile into buf 1
    STAGE_TILE(1, t + 1);
    ALOAD;
    COMPUTE_TILE(0);
    EPILOGUE;
    __syncthreads();
    // odd tile (buf 1); prefetch next even tile into buf 0
    if (tp + 1 < ntiles / 2) STAGE_TILE(0, t + 2);
    ALOAD;
    COMPUTE_TILE(1);
    EPILOGUE;
    __syncthreads();
  }

  // ---- merge laneHi groups (shfl), then the two row-half waves (via Sb) ----
  float* redM = (float*)Sb;            // [2][128]
  float* redS = (float*)(Sb + 1024);   // [2][128]
#pragma unroll
  for (int c = 0; c < 2; ++c) {
#pragma unroll
    for (int off = 16; off <= 32; off <<= 1) {
      float om = __shfl_xor(m_run[c], off);
      float os = __shfl_xor(s_run[c], off);
      float nm = fmaxf(m_run[c], om);
      s_run[c] = s_run[c] * fast_exp2(m_run[c] - nm) + os * fast_exp2(om - nm);
      m_run[c] = nm;
    }
    if (laneHi == 0) {
      redM[wr * 128 + wc * 32 + c * 16 + laneLo] = m_run[c];
      redS[wr * 128 + wc * 32 + c * 16 + laneLo] = s_run[c];
    }
  }
  __syncthreads();
  if (tid < CG) {
    float m0 = redM[tid], m1 = redM[128 + tid];
    float s0 = redS[tid], s1 = redS[128 + tid];
    float Mx = fmaxf(m0, m1);
    float Sx = s0 * fast_exp2(m0 - Mx) + s1 * fast_exp2(m1 - Mx);
    part[(size_t)y * Mtot + col0 + tid] = make_float2(Mx, Sx);
  }
}

// 32 blocks: merge NCH partials/col, subtract b2 term, lse, reduce, atomicAdd.
__global__ __launch_bounds__(256) void lse_finish(const float2* __restrict__ part,
                                                  const float* __restrict__ bLp,
                                                  int NB, int Mtot,
                                                  float* __restrict__ out) {
  const int m = blockIdx.x * blockDim.x + threadIdx.x;
  float mx = -1e30f, s = 0.f;
  for (int b = 0; b < NB; ++b) {
    float2 p = part[(size_t)b * Mtot + m];
    float nm = fmaxf(mx, p.x);
    s = s * fast_exp2(mx - nm) + p.y * fast_exp2(p.x - nm);
    mx = nm;
  }
  float v = mx + __log2f(s) - bLp[m];
#pragma unroll
  for (int off = 32; off >= 1; off >>= 1) v += __shfl_xor(v, off);
  __shared__ float red[4];
  if ((threadIdx.x & 63) == 0) red[threadIdx.x >> 6] = v;
  __syncthreads();
  if (threadIdx.x == 0)
    atomicAdd(out, -LN2 * (red[0] + red[1] + red[2] + red[3]) / (float)Mtot);
}

extern "C" void kernel_launch(void* const* d_in, const int* in_sizes, int n_in,
                              void* d_out, int out_size, void* d_ws, size_t ws_size,
                              hipStream_t stream) {
  const float* mean = (const float*)d_in[0];
  const float* e    = (const float*)d_in[1];
  const int* sigma  = (const int*)d_in[2];
  const int N_ = in_sizes[0] / Z;  // 32768
  const int M_ = in_sizes[1] / Z;  // 8192
  const int chRows = N_ / NCH;     // 2048

  char* ws = (char*)d_ws;
  unsigned char* Abf = (unsigned char*)ws; ws += (size_t)N_ * Z;
  unsigned char* Bbf = (unsigned char*)ws; ws += (size_t)M_ * Z;
  float* nrm = (float*)ws;                 ws += (size_t)(N_ + M_) * sizeof(float);
  float2* part = (float2*)ws;              // NCH * M_ float2 = 1 MB

  hipMemsetAsync(d_out, 0, sizeof(float), stream);
  prep_kernel<<<(N_ + M_) / 8, 256, 0, stream>>>(mean, e, Abf, Bbf, nrm, sigma, N_, M_);
  gemm_lse_kernel<<<(M_ / CG) * NCH, 512, 0, stream>>>(Abf, Bbf, nrm, part, M_, chRows);
  lse_finish<<<M_ / 256, 256, 0, stream>>>(part, nrm + N_, NCH, M_, (float*)d_out);
}

// Round 9
// 185.161 us; speedup vs baseline: 2.2295x; 2.2295x over previous
//
#include <hip/hip_runtime.h>
#include <hip/hip_bf16.h>
#include <cstdint>
#include <cstddef>

#define Z 256      // latent dim (K); also bytes per fp8 row
#define CG 128     // e-columns per block
#define RT 64      // mean-rows per tile
#define NCH 8      // N chunks (grid = 64 x 8 = 512 = exactly 2 blocks/CU)
#define LOG2E 1.4426950408889634f
#define LN2 0.6931471805599453f

typedef __attribute__((ext_vector_type(4))) float f32x4;
typedef long long fp8v8;                                   // 8 fp8 = 2 VGPR
typedef __attribute__((ext_vector_type(2))) long long fp8v16;  // 16 fp8 = 4 VGPR

#define GLOAD_LDS16(g, l)                                                              \
  __builtin_amdgcn_global_load_lds((const __attribute__((address_space(1))) void*)(g), \
                                   (__attribute__((address_space(3))) void*)(l), 16, 0, 0)

__device__ __forceinline__ float fast_exp2(float x) {
#if __has_builtin(__builtin_amdgcn_exp2f)
  return __builtin_amdgcn_exp2f(x);
#else
  float r;
  asm("v_exp_f32 %0, %1" : "=v"(r) : "v"(x));
  return r;
#endif
}

// prep: fp32 -> fp8 e4m3 scaled by sqrt(c1), K-PERMUTED row layout
// (byte k -> pos 64*((k>>3)&3) + 8*(k>>5) + (k&7)), plus k2 * row-sum-of-squares.
// Lane handles k = lane32*8..+7 (all same h,kk) -> one 8B store at permuted pos.
__global__ __launch_bounds__(256) void prep_kernel(const float* __restrict__ mean,
                                                   const float* __restrict__ e,
                                                   unsigned char* __restrict__ Abf,
                                                   unsigned char* __restrict__ Bbf,
                                                   float* __restrict__ nrm,
                                                   const int* __restrict__ sigma_p,
                                                   int Nr, int Mr) {
  const float sgm = (float)(*sigma_p);
  const float c1 = LOG2E / (sgm * sgm);
  const float k2 = 0.5f * c1;
  const float sc = sqrtf(c1);
  const int tid = threadIdx.x;
  const int lane32 = tid & 31;
  const int row = blockIdx.x * 8 + (tid >> 5);
  if (row >= Nr + Mr) return;
  const float* src = (row < Nr) ? (mean + (size_t)row * Z) : (e + (size_t)(row - Nr) * Z);
  unsigned char* d = (row < Nr) ? (Abf + (size_t)row * Z) : (Bbf + (size_t)(row - Nr) * Z);
  const float4 v0 = *reinterpret_cast<const float4*>(src + lane32 * 8);
  const float4 v1 = *reinterpret_cast<const float4*>(src + lane32 * 8 + 4);
  float s = v0.x * v0.x + v0.y * v0.y + v0.z * v0.z + v0.w * v0.w +
            v1.x * v1.x + v1.y * v1.y + v1.z * v1.z + v1.w * v1.w;
  s += __shfl_xor(s, 1); s += __shfl_xor(s, 2); s += __shfl_xor(s, 4);
  s += __shfl_xor(s, 8); s += __shfl_xor(s, 16);
  if (lane32 == 0) nrm[row] = k2 * s;
  int r0 = __builtin_amdgcn_cvt_pk_fp8_f32(v0.x * sc, v0.y * sc, 0, false);
  r0 = __builtin_amdgcn_cvt_pk_fp8_f32(v0.z * sc, v0.w * sc, r0, true);
  int r1 = __builtin_amdgcn_cvt_pk_fp8_f32(v1.x * sc, v1.y * sc, 0, false);
  r1 = __builtin_amdgcn_cvt_pk_fp8_f32(v1.z * sc, v1.w * sc, r1, true);
  *reinterpret_cast<int2*>(d + ((lane32 & 3) << 6) + ((lane32 >> 2) << 3)) =
      make_int2(r0, r1);
}

// stage one full 64-row x 256-B fp8 A tile (16 KB) into buffer BUF (literal 0/1).
// LDS[r][p] = G[r][p ^ (r&7)] at 16B-slot granularity (linear LDS dest).
#define STAGE_TILE(BUF, T)                                  \
  {                                                         \
    const char* g = Ab8 + (size_t)(T) * 16384;              \
    GLOAD_LDS16(g + gof0, Sb + (BUF) * 16384 + o0);         \
    GLOAD_LDS16(g + gof1, Sb + (BUF) * 16384 + o1);         \
  }

// 32 MFMA for one tile from buffer BUF: 4 kk-pairs x (2 b128 reads + 8 MFMA).
// Read slot s at LDS slot s^(row&7): the wave's 64 lanes tile the 8 slots
// uniformly (8 lanes each) -> conflict-free ds_read_b128.
#define COMPUTE_TILE(BUF)                                                             \
  {                                                                                   \
    _Pragma("unroll") for (int kp = 0; kp < 4; ++kp) {                                \
      fp8v16 at[2];                                                                   \
      const int slot = laneHi * 4 + kp;                                               \
      _Pragma("unroll") for (int a = 0; a < 2; ++a) {                                 \
        const int ro = wr * 32 + a * 16 + laneLo;                                     \
        at[a] = *reinterpret_cast<const fp8v16*>(                                     \
            Sb + (BUF) * 16384 + ro * 256 + ((slot ^ (ro & 7)) << 4));                \
      }                                                                               \
      _Pragma("unroll") for (int a = 0; a < 2; ++a)                                   \
          _Pragma("unroll") for (int c = 0; c < 2; ++c) {                             \
        acc[a][c] = __builtin_amdgcn_mfma_f32_16x16x32_fp8_fp8(                       \
            at[a][0], bfr[c][2 * kp],                                                 \
            (kp == 0) ? f32x4{0.f, 0.f, 0.f, 0.f} : acc[a][c], 0, 0, 0);              \
        acc[a][c] = __builtin_amdgcn_mfma_f32_16x16x32_fp8_fp8(                       \
            at[a][1], bfr[c][2 * kp + 1], acc[a][c], 0, 0, 0);                        \
      }                                                                               \
    }                                                                                 \
  }

// online-LSE over the finished tile: 8 logits/lane per col-frag (pre-scaled;
// per-column b2 term factored out -> applied in lse_finish)
#define EPILOGUE                                                                      \
  {                                                                                   \
    _Pragma("unroll") for (int c = 0; c < 2; ++c) {                                   \
      float w0 = acc[0][c][0] - av0.x, w1 = acc[0][c][1] - av0.y;                     \
      float w2 = acc[0][c][2] - av0.z, w3 = acc[0][c][3] - av0.w;                     \
      float w4 = acc[1][c][0] - av1.x, w5 = acc[1][c][1] - av1.y;                     \
      float w6 = acc[1][c][2] - av1.z, w7 = acc[1][c][3] - av1.w;                     \
      float mx = fmaxf(fmaxf(fmaxf(w0, w1), fmaxf(w2, w3)),                           \
                       fmaxf(fmaxf(w4, w5), fmaxf(w6, w7)));                          \
      float nm = fmaxf(m_run[c], mx);                                                 \
      float ss = fast_exp2(w0 - nm) + fast_exp2(w1 - nm) + fast_exp2(w2 - nm) +       \
                 fast_exp2(w3 - nm) + fast_exp2(w4 - nm) + fast_exp2(w5 - nm) +       \
                 fast_exp2(w6 - nm) + fast_exp2(w7 - nm);                             \
      s_run[c] = s_run[c] * fast_exp2(m_run[c] - nm) + ss;                            \
      m_run[c] = nm;                                                                  \
    }                                                                                 \
  }

#define ALOAD                                                  \
  av0 = *reinterpret_cast<const float4*>(aptr);                \
  av1 = *reinterpret_cast<const float4*>(aptr + 16);           \
  aptr += 64;

// Column-strip fused GEMM (fp8 e4m3, K-permuted) + online logsumexp.
// Full-tile double buffer (2x16 KB), one __syncthreads per tile.
// 8 waves (2r x 4c); B panel register-resident; launch_bounds(512,4)
// (128-VGPR budget; (512,8) forced 64 and spilled catastrophically, r8).
__global__ __launch_bounds__(512, 4) void gemm_lse_kernel(
    const unsigned char* __restrict__ Abf,  // [N][Z] fp8, scaled, K-permuted
    const unsigned char* __restrict__ Bbf,  // [M][Z] fp8
    const float* __restrict__ nrm,          // [N+M]: k2*a2 then k2*b2
    float2* __restrict__ part,              // [NCH][M] (max2, sumexp2), b2-uncorrected
    int Mtot, int chRows) {
  __shared__ __align__(16) char Sb[32768];  // B staged through it, then A dbuf

  const int tid = threadIdx.x;
  const int lane = tid & 63;
  const int w = tid >> 6;
  const int wr = w >> 2, wc = w & 3;
  const int laneLo = lane & 15, laneHi = lane >> 4;

  const int id = blockIdx.x;
  const int y = id & 7;    // XCD-affine: chunk y pinned to xcd id&7
  const int x = id >> 3;
  const int row0base = y * chRows;
  const int col0 = x * CG;
  const int ntiles = chRows / RT;  // 64

  // ---- stage full B panel (128 cols x 256 B = 32 KB), swizzled source ----
#pragma unroll
  for (int i = 0; i < 4; ++i) {
    int o = i * 8192 + tid * 16;
    int r = o >> 8;
    int p = (o >> 4) & 15;
    GLOAD_LDS16((const char*)Bbf + (size_t)(col0 + r) * Z + ((p ^ (r & 7)) << 4),
                Sb + o);
  }
  __syncthreads();
  fp8v8 bfr[2][8];
#pragma unroll
  for (int c = 0; c < 2; ++c) {
    const int rb = wc * 32 + c * 16 + laneLo;
#pragma unroll
    for (int kp = 0; kp < 4; ++kp) {
      const int slot = laneHi * 4 + kp;
      fp8v16 v = *reinterpret_cast<const fp8v16*>(Sb + rb * 256 +
                                                  ((slot ^ (rb & 7)) << 4));
      bfr[c][2 * kp] = v[0];
      bfr[c][2 * kp + 1] = v[1];
    }
  }
  __syncthreads();  // bfr safely in regs before A-stages overwrite Sb

  // ---- per-thread A staging offsets (2 gload_lds per tile) ----
  const char* Ab8 = (const char*)Abf + (size_t)row0base * Z;
  const int o0 = tid * 16, o1 = 8192 + tid * 16;
  const int r_0 = o0 >> 8, p_0 = (o0 >> 4) & 15;
  const int r_1 = o1 >> 8, p_1 = (o1 >> 4) & 15;
  const int gof0 = r_0 * 256 + ((p_0 ^ (r_0 & 7)) << 4);
  const int gof1 = r_1 * 256 + ((p_1 ^ (r_1 & 7)) << 4);
  const float* aptr = nrm + row0base + wr * 32 + laneHi * 4;

  f32x4 acc[2][2];
  float m_run[2] = {-1e30f, -1e30f};
  float s_run[2] = {0.f, 0.f};
  float4 av0, av1;

  STAGE_TILE(0, 0);
  __syncthreads();  // tile 0 resident

  for (int tp = 0; tp < ntiles / 2; ++tp) {
    const int t = tp * 2;
    // even tile (buf 0); prefetch odd tile into buf 1
    STAGE_TILE(1, t + 1);
    ALOAD;
    COMPUTE_TILE(0);
    EPILOGUE;
    __syncthreads();
    // odd tile (buf 1); prefetch next even tile into buf 0
    if (tp + 1 < ntiles / 2) STAGE_TILE(0, t + 2);
    ALOAD;
    COMPUTE_TILE(1);
    EPILOGUE;
    __syncthreads();
  }

  // ---- merge laneHi groups (shfl), then the two row-half waves (via Sb) ----
  float* redM = (float*)Sb;            // [2][128]
  float* redS = (float*)(Sb + 1024);   // [2][128]
#pragma unroll
  for (int c = 0; c < 2; ++c) {
#pragma unroll
    for (int off = 16; off <= 32; off <<= 1) {
      float om = __shfl_xor(m_run[c], off);
      float os = __shfl_xor(s_run[c], off);
      float nm = fmaxf(m_run[c], om);
      s_run[c] = s_run[c] * fast_exp2(m_run[c] - nm) + os * fast_exp2(om - nm);
      m_run[c] = nm;
    }
    if (laneHi == 0) {
      redM[wr * 128 + wc * 32 + c * 16 + laneLo] = m_run[c];
      redS[wr * 128 + wc * 32 + c * 16 + laneLo] = s_run[c];
    }
  }
  __syncthreads();
  if (tid < CG) {
    float m0 = redM[tid], m1 = redM[128 + tid];
    float s0 = redS[tid], s1 = redS[128 + tid];
    float Mx = fmaxf(m0, m1);
    float Sx = s0 * fast_exp2(m0 - Mx) + s1 * fast_exp2(m1 - Mx);
    part[(size_t)y * Mtot + col0 + tid] = make_float2(Mx, Sx);
  }
}

// 32 blocks: merge NCH partials/col, subtract b2 term, lse, reduce, atomicAdd.
__global__ __launch_bounds__(256) void lse_finish(const float2* __restrict__ part,
                                                  const float* __restrict__ bLp,
                                                  int NB, int Mtot,
                                                  float* __restrict__ out) {
  const int m = blockIdx.x * blockDim.x + threadIdx.x;
  float mx = -1e30f, s = 0.f;
  for (int b = 0; b < NB; ++b) {
    float2 p = part[(size_t)b * Mtot + m];
    float nm = fmaxf(mx, p.x);
    s = s * fast_exp2(mx - nm) + p.y * fast_exp2(p.x - nm);
    mx = nm;
  }
  float v = mx + __log2f(s) - bLp[m];
#pragma unroll
  for (int off = 32; off >= 1; off >>= 1) v += __shfl_xor(v, off);
  __shared__ float red[4];
  if ((threadIdx.x & 63) == 0) red[threadIdx.x >> 6] = v;
  __syncthreads();
  if (threadIdx.x == 0)
    atomicAdd(out, -LN2 * (red[0] + red[1] + red[2] + red[3]) / (float)Mtot);
}

extern "C" void kernel_launch(void* const* d_in, const int* in_sizes, int n_in,
                              void* d_out, int out_size, void* d_ws, size_t ws_size,
                              hipStream_t stream) {
  const float* mean = (const float*)d_in[0];
  const float* e    = (const float*)d_in[1];
  const int* sigma  = (const int*)d_in[2];
  const int N_ = in_sizes[0] / Z;  // 32768
  const int M_ = in_sizes[1] / Z;  // 8192
  const int chRows = N_ / NCH;     // 4096

  char* ws = (char*)d_ws;
  unsigned char* Abf = (unsigned char*)ws; ws += (size_t)N_ * Z;
  unsigned char* Bbf = (unsigned char*)ws; ws += (size_t)M_ * Z;
  float* nrm = (float*)ws;                 ws += (size_t)(N_ + M_) * sizeof(float);
  float2* part = (float2*)ws;              // NCH * M_ float2 = 512 KB

  hipMemsetAsync(d_out, 0, sizeof(float), stream);
  prep_kernel<<<(N_ + M_) / 8, 256, 0, stream>>>(mean, e, Abf, Bbf, nrm, sigma, N_, M_);
  gemm_lse_kernel<<<(M_ / CG) * NCH, 512, 0, stream>>>(Abf, Bbf, nrm, part, M_, chRows);
  lse_finish<<<M_ / 256, 256, 0, stream>>>(part, nrm + N_, NCH, M_, (float*)d_out);
}